// Round 1
// 239.906 us; speedup vs baseline: 1.0130x; 1.0130x over previous
//
#include <hip/hip_runtime.h>

// Problem constants (fixed by the reference: B=16, D=256, K=64, H=W=96)
#define NDIM  256
#define NK    64
#define NPIX  9216
#define NB    16
#define TN    64           // pixels per tile
#define NW    32           // writer blocks per batch (single-pass: 512 blocks)
#define GRID  (NB*NW)      // 512 = exactly 2 blocks/CU resident -> one pass

typedef _Float16 half2_t __attribute__((ext_vector_type(2)));
typedef _Float16 half8_t __attribute__((ext_vector_type(8)));
typedef float    f32x4  __attribute__((ext_vector_type(4)));

__device__ __forceinline__ float fdot2(half2_t a, half2_t b, float c) {
  return __builtin_amdgcn_fdot2(a, b, c, false);
}

// Workgroup barrier that drains only LDS (lgkmcnt), never vmcnt.
// __syncthreads() emits "s_waitcnt vmcnt(0) lgkmcnt(0)" before s_barrier,
// which force-completed the 64-load register prefetch at B3 (one barrier
// after issue) and left HBM idle from B3 to the next tile's B2. In-flight
// VMEM here is only thread-private register loads (xv prefetch), so
// skipping the vmcnt drain is race-free; the compiler still inserts
// counted vmcnt(N) waits at each xv consumption point.
#define BAR() asm volatile("s_waitcnt lgkmcnt(0)\n\ts_barrier" ::: "memory")

// ws layout (float offsets):
#define OFF_CH     0
#define OFF_C2     (NK * NDIM / 2)
#define OFF_ASUM   (OFF_C2 + NK)
#define OFF_APART  (OFF_ASUM + NB * NK)
#define OFF_EPART  (OFF_APART + GRID * NK)
#define WS_NEED    ((size_t)OFF_EPART * 4 + (size_t)GRID * NK * NDIM * 2)

// ---- c2[k] + f16 codeword pack ----
__global__ void c2ch_kernel(const float* __restrict__ Cw, float* __restrict__ c2,
                            _Float16* __restrict__ ChH) {
  const int k = blockIdx.x, t = threadIdx.x;
  const float4 v = *(const float4*)(Cw + k * NDIM + 4 * t);
  half2_t h0; h0.x = (_Float16)v.x; h0.y = (_Float16)v.y;
  half2_t h1; h1.x = (_Float16)v.z; h1.y = (_Float16)v.w;
  *(half2_t*)&ChH[k * NDIM + 4 * t]     = h0;
  *(half2_t*)&ChH[k * NDIM + 4 * t + 2] = h1;
  float s = v.x*v.x + v.y*v.y + v.z*v.z + v.w*v.w;
#pragma unroll
  for (int o = 32; o; o >>= 1) s += __shfl_down(s, o);
  if (t == 0) c2[k] = s;
}

// ---- fused MFMA kernel ----
// R7: single-pass grid (512 blocks, 5/4 uneven tiles), lgkm-only barriers
// (prefetch loads survive across B3/B4/B1), balanced asum across 4 waves.
__global__ __launch_bounds__(256, 2) void encode_main(
    const float* __restrict__ X, const _Float16* __restrict__ ChH,
    const float* __restrict__ scale, const float* __restrict__ c2,
    void* __restrict__ Eout, float* __restrict__ Aout, int mode)
{
  __shared__ _Float16 XbS[32 * 66 * 8];   // Xb[d>>3][p][d&7], 33,792 B
  __shared__ _Float16 Al[NK][72];         // softmax weights [k][p]
  __shared__ float red2[4][TN];
  __shared__ float redM[4][TN];
  __shared__ float redS[4][TN];

  const int tid  = threadIdx.x;
  const int w    = __builtin_amdgcn_readfirstlane(tid >> 6);
  const int lane = tid & 63;
  const int m    = lane & 15, quad = lane >> 4;
  const int b    = blockIdx.x >> 5;        // /NW
  const int wid  = blockIdx.x & 31;        // %NW
  // 144 tiles/batch over 32 blocks: first 16 blocks take 5 tiles, rest 4.
  const int ntiles = (wid < 16) ? 5 : 4;
  const int pix0   = (wid * 4 + (wid < 16 ? wid : 16)) * TN;
  const float* Xbase = X + (size_t)b * NDIM * NPIX;
  const int kbase = w * 16;

  // phase-1 A-frags (codewords): tile-invariant, registers
  half8_t af1[8];
#pragma unroll
  for (int ks = 0; ks < 8; ++ks)
    af1[ks] = *(const half8_t*)(ChH + (kbase + m) * NDIM + ks * 32 + quad * 8);

  const float4 scv = *(const float4*)(scale + kbase + quad * 4);
  const float4 c2v = *(const float4*)(c2 + kbase + quad * 4);
  const float sc[4] = {scv.x, scv.y, scv.z, scv.w};
  const float sq[4] = {scv.x * c2v.x, scv.y * c2v.y, scv.z * c2v.z, scv.w * c2v.w};

  f32x4 acc_e[4][4];
#pragma unroll
  for (int i = 0; i < 4; ++i)
#pragma unroll
    for (int j = 0; j < 4; ++j)
      acc_e[i][j] = (f32x4){0.f, 0.f, 0.f, 0.f};
  float asum_acc = 0.f;

  // ---- prefetch tile 0 into registers ----
  float xv[64];
  {
    const float* Xg = Xbase + (size_t)(w * 64) * NPIX + pix0 + lane;
#pragma unroll
    for (int i = 0; i < 64; ++i) xv[i] = Xg[(size_t)i * NPIX];
  }

  for (int tt = 0; tt < ntiles; ++tt) {
    BAR();                             // B1: prev tile's phase-3 reads done

    // ---- stage from prefetch regs: cvt f16 + xsq, LDS b128 writes ----
    // (compiler emits counted vmcnt waits per xv group here; loads that
    // haven't landed yet only stall their own consumer)
    {
      float xsq = 0.f;
#pragma unroll
      for (int g = 0; g < 8; ++g) {
        half8_t hv;
#pragma unroll
        for (int i = 0; i < 8; ++i) {
          const float v = xv[g * 8 + i];
          hv[i] = (_Float16)v; xsq += v * v;
        }
        *(half8_t*)&XbS[((w * 8 + g) * 66 + lane) * 8] = hv;
      }
      red2[w][lane] = xsq;
    }
    BAR();                             // B2: XbS + red2 visible

    // ---- issue next tile's loads NOW; they stay in flight across
    //      B3/B4/B1 (lgkm-only barriers) until consumed next stage ----
    if (tt + 1 < ntiles) {
      const float* Xg = Xbase + (size_t)(w * 64) * NPIX + pix0 + (tt + 1) * TN + lane;
#pragma unroll
      for (int i = 0; i < 64; ++i) xv[i] = Xg[(size_t)i * NPIX];
    }

    // ---- phase 1 MFMA: S^T[k 16][p 64] per wave ----
    f32x4 accs[4];
#pragma unroll
    for (int nt = 0; nt < 4; ++nt) accs[nt] = (f32x4){0.f, 0.f, 0.f, 0.f};
#pragma unroll
    for (int ks = 0; ks < 8; ++ks) {
#pragma unroll
      for (int nt = 0; nt < 4; ++nt) {
        const half8_t bf = *(const half8_t*)&XbS[((ks * 4 + quad) * 66 + nt * 16 + m) * 8];
        accs[nt] = __builtin_amdgcn_mfma_f32_16x16x32_f16(af1[ks], bf, accs[nt], 0, 0, 0);
      }
    }

    // ---- phase 2: softmax; in-wave shfl + one LDS exchange ----
    float e[4][4], mw[4];
#pragma unroll
    for (int nt = 0; nt < 4; ++nt) {
      const int p = nt * 16 + m;
      const float x2p = red2[0][p] + red2[1][p] + red2[2][p] + red2[3][p];
      float L[4];
      float mx = -3.0e38f;
#pragma unroll
      for (int r = 0; r < 4; ++r) {
        L[r] = sc[r] * x2p - 2.f * sc[r] * accs[nt][r] + sq[r];
        mx = fmaxf(mx, L[r]);
      }
      mx = fmaxf(mx, __shfl_xor(mx, 16));
      mx = fmaxf(mx, __shfl_xor(mx, 32));
      float s = 0.f;
#pragma unroll
      for (int r = 0; r < 4; ++r) { e[nt][r] = __expf(L[r] - mx); s += e[nt][r]; }
      s += __shfl_xor(s, 16);
      s += __shfl_xor(s, 32);
      mw[nt] = mx;
      if (lane < 16) { redM[w][p] = mx; redS[w][p] = s; }
    }
    BAR();                             // B3: cross-wave max/sum exchange
#pragma unroll
    for (int nt = 0; nt < 4; ++nt) {
      const int p = nt * 16 + m;
      const float M = fmaxf(fmaxf(redM[0][p], redM[1][p]),
                            fmaxf(redM[2][p], redM[3][p]));
      const float T = redS[0][p] * __expf(redM[0][p] - M)
                    + redS[1][p] * __expf(redM[1][p] - M)
                    + redS[2][p] * __expf(redM[2][p] - M)
                    + redS[3][p] * __expf(redM[3][p] - M);
      const float norm = __expf(mw[nt] - M) / T;
#pragma unroll
      for (int r = 0; r < 4; ++r)
        Al[kbase + quad * 4 + r][p] = (_Float16)(e[nt][r] * norm);
    }
    BAR();                             // B4: Al visible

    // ---- phase 3 MFMA: E^T[d 64][k 64] per wave ----
#pragma unroll
    for (int ks = 0; ks < 2; ++ks) {
      half8_t ba[4];
#pragma unroll
      for (int kt = 0; kt < 4; ++kt)
        ba[kt] = *(const half8_t*)&Al[kt * 16 + m][ks * 32 + quad * 8];
#pragma unroll
      for (int dt = 0; dt < 4; ++dt) {
        const int c = w * 8 + dt * 2 + (m >> 3);
        const int dlow = m & 7;
        half8_t xa;
#pragma unroll
        for (int j = 0; j < 8; ++j)
          xa[j] = XbS[(c * 66 + ks * 32 + quad * 8 + j) * 8 + dlow];
#pragma unroll
        for (int kt = 0; kt < 4; ++kt)
          acc_e[dt][kt] = __builtin_amdgcn_mfma_f32_16x16x32_f16(xa, ba[kt], acc_e[dt][kt], 0, 0, 0);
      }
    }

    // ---- asum rows: balanced over all 4 waves (16 k each), 4-lane reduce ----
    {
      const half2_t one = {(_Float16)1.f, (_Float16)1.f};
      const int ka = kbase + (lane >> 2);
      const int pa = (lane & 3) * 16;
      float s = 0.f;
#pragma unroll
      for (int lc = 0; lc < 2; ++lc) {
        const half8_t sv = *(const half8_t*)&Al[ka][pa + lc * 8];
        s = fdot2(__builtin_shufflevector(sv, sv, 0, 1), one, s);
        s = fdot2(__builtin_shufflevector(sv, sv, 2, 3), one, s);
        s = fdot2(__builtin_shufflevector(sv, sv, 4, 5), one, s);
        s = fdot2(__builtin_shufflevector(sv, sv, 6, 7), one, s);
      }
      s += __shfl_xor(s, 1);
      s += __shfl_xor(s, 2);
      asum_acc += s;                   // valid on lanes with (lane&3)==0
    }
  }

  // ---- epilogue: transpose frags through LDS (XbS dead -> alias as Et) ----
  BAR();
  _Float16* Et = XbS;                  // [64][264]
#pragma unroll
  for (int dt = 0; dt < 4; ++dt)
#pragma unroll
    for (int kt = 0; kt < 4; ++kt)
#pragma unroll
      for (int r = 0; r < 4; ++r) {
        const int k = kt * 16 + m;               // C/D: col=lane&15 -> k
        const int d = w * 64 + dt * 16 + quad * 4 + r;
        Et[k * 264 + d] = (_Float16)acc_e[dt][kt][r];
      }
  BAR();
  const int ko = tid >> 2, cq = tid & 3;
  if (mode) {
    _Float16* Ebk = (_Float16*)Eout + (size_t)blockIdx.x * (NK * NDIM);
#pragma unroll
    for (int g = 0; g < 8; ++g)
      *(half8_t*)&Ebk[ko * NDIM + cq * 64 + g * 8] =
          *(const half8_t*)&Et[ko * 264 + cq * 64 + g * 8];
    if ((lane & 3) == 0)
      Aout[blockIdx.x * NK + kbase + (lane >> 2)] = asum_acc;
  } else {
    float* Ebk = (float*)Eout + (size_t)b * (NK * NDIM);
#pragma unroll
    for (int g = 0; g < 64; ++g)
      atomicAdd(&Ebk[ko * NDIM + cq * 64 + g], (float)Et[ko * 264 + cq * 64 + g]);
    if ((lane & 3) == 0)
      atomicAdd(&Aout[b * NK + kbase + (lane >> 2)], asum_acc);
  }
}

// ---- out = sum_w Epart(f16) - asum*C ; asum fused (redundant L1-hot reads) ----
__global__ void finalize_partials(const _Float16* __restrict__ EpartH,
                                  const float* __restrict__ Apart,
                                  const float* __restrict__ Cw,
                                  float* __restrict__ out) {
  const int g = blockIdx.x * 256 + threadIdx.x;  // half8-group id, 0..32767
  const int i0 = g * 8;
  const int bb = i0 >> 14;
  const int o  = i0 & 16383;           // k*256+d within batch
  const int k  = o >> 8, d = i0 & 255;
  // asum[bb][k]: 32 scalar loads, identical across the 32 threads sharing
  // (bb,k) in a wave -> broadcast from L1; replaces the asum_reduce launch.
  float a = 0.f;
#pragma unroll 8
  for (int w = 0; w < NW; ++w) a += Apart[(bb * NW + w) * NK + k];
  float s[8];
#pragma unroll
  for (int j = 0; j < 8; ++j) s[j] = 0.f;
  const _Float16* base = EpartH + (((size_t)bb * NW) << 14) + o;
#pragma unroll 4
  for (int w = 0; w < NW; ++w) {
    const half8_t v = *(const half8_t*)(base + ((size_t)w << 14));
#pragma unroll
    for (int j = 0; j < 8; ++j) s[j] += (float)v[j];
  }
  const float4 c0 = *(const float4*)(Cw + k * NDIM + d);
  const float4 c1 = *(const float4*)(Cw + k * NDIM + d + 4);
  float4 r0, r1;
  r0.x = s[0] - a * c0.x; r0.y = s[1] - a * c0.y;
  r0.z = s[2] - a * c0.z; r0.w = s[3] - a * c0.w;
  r1.x = s[4] - a * c1.x; r1.y = s[5] - a * c1.y;
  r1.z = s[6] - a * c1.z; r1.w = s[7] - a * c1.w;
  *(float4*)(out + i0)     = r0;
  *(float4*)(out + i0 + 4) = r1;
}

// ---- out = E_acc - asum*C (atomic-fallback mode) ----
__global__ void finalize_atomic(const float* __restrict__ E_acc,
                                const float* __restrict__ asum,
                                const float* __restrict__ Cw,
                                float* __restrict__ out) {
  const int i = blockIdx.x * 256 + threadIdx.x;
  const int d = i & 255;
  const int k = (i >> 8) & 63;
  const int bb = i >> 14;
  out[i] = E_acc[i] - asum[bb * NK + k] * Cw[k * NDIM + d];
}

extern "C" void kernel_launch(void* const* d_in, const int* in_sizes, int n_in,
                              void* d_out, int out_size, void* d_ws, size_t ws_size,
                              hipStream_t stream) {
  const float* X     = (const float*)d_in[0];
  const float* Cw    = (const float*)d_in[1];
  const float* scale = (const float*)d_in[2];
  float* out = (float*)d_out;

  float* wsf = (float*)d_ws;
  _Float16* ChH = (_Float16*)(wsf + OFF_CH);
  float* c2     = wsf + OFF_C2;
  float* asum   = wsf + OFF_ASUM;
  float* Apart  = wsf + OFF_APART;

  c2ch_kernel<<<NK, 64, 0, stream>>>(Cw, c2, ChH);
  if (ws_size >= WS_NEED) {
    _Float16* EpartH = (_Float16*)(wsf + OFF_EPART);
    encode_main<<<GRID, 256, 0, stream>>>(X, ChH, scale, c2, EpartH, Apart, 1);
    finalize_partials<<<(NB*NK*NDIM)/(256*8), 256, 0, stream>>>(EpartH, Apart, Cw, out);
  } else {
    float* E_acc = wsf + OFF_APART;   // fallback: fp32 atomic accumulator
    hipMemsetAsync(wsf + OFF_ASUM, 0,
                   (size_t)(NB*NK + GRID*NK + NB*NK*NDIM) * sizeof(float), stream);
    encode_main<<<GRID, 256, 0, stream>>>(X, ChH, scale, c2, E_acc, asum, 0);
    finalize_atomic<<<(NB*NK*NDIM)/256, 256, 0, stream>>>(E_acc, asum, Cw, out);
  }
}